// Round 7
// baseline (215.293 us; speedup 1.0000x reference)
//
#include <hip/hip_runtime.h>

#define Bn 1024
#define Pn 128
#define Fn 512
#define Dn 256
#define THETA 1e-7f
#define BP (Bn * Pn)
#define SB 8            // F-split of reduction kernel
#define FCB (Fn / SB)   // 64

// ===========================================================================
// DIAGNOSTIC ROUND: round-1 kernels, each with a runtime `reps` multiplier.
// The rep loop recomputes the same result (asm memory clobber prevents CSE);
// stores happen once after the loop -> output identical to round 1.
// Purpose: push each dispatch above the 40us fillBuffer floor so rocprof's
// top-5 finally shows per-kernel dur/VALUBusy/LDS_CONFLICT/FETCH_SIZE.
// ===========================================================================

// ---------------------------------------------------------------------------
// GEMM: C = [x; prototypes] @ fb^T.  64x64 tile, 256 thr, 4x4/thread.
// ---------------------------------------------------------------------------
__global__ __launch_bounds__(256)
void gemm_feat(const float* __restrict__ x, const float* __restrict__ prot,
               const float* __restrict__ fb, float* __restrict__ xf,
               float* __restrict__ pfT, int reps)
{
    __shared__ float As[64][68];
    __shared__ float Fs[64][68];
    const int tid = threadIdx.x;
    const int rb  = blockIdx.y * 64;
    const int cb  = blockIdx.x * 64;
    const int tx  = tid & 15;
    const int ty  = tid >> 4;
    const int lr  = tid >> 2;
    const int lk  = tid & 3;

    float acc[4][4];

    #pragma clang loop unroll(disable)
    for (int rep = 0; rep < reps; ++rep) {
        asm volatile("" ::: "memory");
        #pragma unroll
        for (int i = 0; i < 4; ++i)
            #pragma unroll
            for (int j = 0; j < 4; ++j) acc[i][j] = 0.f;

        for (int k0 = 0; k0 < Dn; k0 += 64) {
            #pragma unroll
            for (int q = 0; q < 4; ++q) {
                const int kk = lk + q * 4;
                const int r  = rb + lr;
                const float* asrc = (r < Bn) ? (x + (size_t)r * Dn)
                                             : (prot + (size_t)(r - Bn) * Dn);
                float4 av = *(const float4*)(asrc + k0 + kk * 4);
                float4 fv = *(const float4*)(fb + (size_t)(cb + lr) * Dn + k0 + kk * 4);
                As[kk*4+0][lr] = av.x; As[kk*4+1][lr] = av.y;
                As[kk*4+2][lr] = av.z; As[kk*4+3][lr] = av.w;
                Fs[kk*4+0][lr] = fv.x; Fs[kk*4+1][lr] = fv.y;
                Fs[kk*4+2][lr] = fv.z; Fs[kk*4+3][lr] = fv.w;
            }
            __syncthreads();
            #pragma unroll 8
            for (int k = 0; k < 64; ++k) {
                float4 a = *(const float4*)&As[k][ty * 4];
                float4 f = *(const float4*)&Fs[k][tx * 4];
                const float aa[4] = {a.x, a.y, a.z, a.w};
                const float ff[4] = {f.x, f.y, f.z, f.w};
                #pragma unroll
                for (int i = 0; i < 4; ++i)
                    #pragma unroll
                    for (int j = 0; j < 4; ++j)
                        acc[i][j] = fmaf(aa[i], ff[j], acc[i][j]);
            }
            __syncthreads();
        }
    }

    #pragma unroll
    for (int i = 0; i < 4; ++i) {
        const int r = rb + ty * 4 + i;
        #pragma unroll
        for (int j = 0; j < 4; ++j) {
            const int c = cb + tx * 4 + j;
            if (r < Bn) xf[(size_t)r * Fn + c] = acc[i][j];
            else        pfT[(size_t)c * Pn + (r - Bn)] = acc[i][j];
        }
    }
}

// ---------------------------------------------------------------------------
// Tversky reduction over one F-chunk (round-1 exact math).
// ---------------------------------------------------------------------------
__global__ __launch_bounds__(256)
void tversky_main(const float* __restrict__ xf, const float* __restrict__ pfT,
                  const float* __restrict__ alpha_p, const float* __restrict__ beta_p,
                  float* __restrict__ partI, float* __restrict__ partW, int reps)
{
    const int tid = threadIdx.x;
    const int tx  = tid & 7;
    const int ty  = tid >> 3;
    const int p0  = blockIdx.y * 32 + tx * 4;
    const int b0  = blockIdx.x * 64 + ty * 2;
    const int s   = blockIdx.z;
    const int f0  = s * FCB;

    float aI[2][4], aM[2][4], aX[2][4], aP[2][4];

    #pragma clang loop unroll(disable)
    for (int rep = 0; rep < reps; ++rep) {
        asm volatile("" ::: "memory");
        #pragma unroll
        for (int i = 0; i < 2; ++i)
            #pragma unroll
            for (int q = 0; q < 4; ++q) {
                aI[i][q] = 0.f; aM[i][q] = 0.f; aX[i][q] = 0.f; aP[i][q] = 0.f;
            }

        for (int f = f0; f < f0 + FCB; f += 4) {
            float4 pr[4];
            #pragma unroll
            for (int j = 0; j < 4; ++j)
                pr[j] = *(const float4*)(pfT + (size_t)(f + j) * Pn + p0);
            float4 xr[2];
            #pragma unroll
            for (int i = 0; i < 2; ++i)
                xr[i] = *(const float4*)(xf + (size_t)(b0 + i) * Fn + f);

            #pragma unroll
            for (int j = 0; j < 4; ++j) {
                const float pv[4] = {pr[j].x, pr[j].y, pr[j].z, pr[j].w};
                float rp[4], bp[4];
                #pragma unroll
                for (int q = 0; q < 4; ++q) {
                    rp[q] = fmaxf(pv[q], 0.f);
                    bp[q] = (pv[q] > 0.f) ? 1.f : 0.f;
                }
                #pragma unroll
                for (int i = 0; i < 2; ++i) {
                    const float* xcomp = (const float*)&xr[i];
                    const float xv = xcomp[j];
                    const float rx = fmaxf(xv, 0.f);
                    const float bx = (xv > 0.f) ? 1.f : 0.f;
                    #pragma unroll
                    for (int q = 0; q < 4; ++q) {
                        aI[i][q]  = fmaf(rx, rp[q], aI[i][q]);
                        aM[i][q] += fminf(rx, rp[q]);
                        aX[i][q]  = fmaf(rx, bp[q], aX[i][q]);
                        aP[i][q]  = fmaf(rp[q], bx, aP[i][q]);
                    }
                }
            }
        }
    }

    const float alpha = *alpha_p;
    const float beta  = *beta_p;
    #pragma unroll
    for (int i = 0; i < 2; ++i) {
        #pragma unroll
        for (int q = 0; q < 4; ++q) {
            const size_t idx = (size_t)s * BP + (size_t)(b0 + i) * Pn + (p0 + q);
            partI[idx] = aI[i][q];
            partW[idx] = alpha * (aX[i][q] - aM[i][q])
                       + beta  * (aP[i][q] - aM[i][q]);
        }
    }
}

// ---------------------------------------------------------------------------
// Epilogue: reduce SB partials, compute ratio.
// ---------------------------------------------------------------------------
__global__ __launch_bounds__(256)
void tversky_epi(const float* __restrict__ partI, const float* __restrict__ partW,
                 float* __restrict__ out, int reps)
{
    const int idx = blockIdx.x * 256 + threadIdx.x;
    float I, W;
    #pragma clang loop unroll(disable)
    for (int rep = 0; rep < reps; ++rep) {
        asm volatile("" ::: "memory");
        I = 0.f; W = 0.f;
        #pragma unroll
        for (int s = 0; s < SB; ++s) {
            I += partI[(size_t)s * BP + idx];
            W += partW[(size_t)s * BP + idx];
        }
    }
    out[idx] = I / (I + W + THETA);
}

extern "C" void kernel_launch(void* const* d_in, const int* in_sizes, int n_in,
                              void* d_out, int out_size, void* d_ws, size_t ws_size,
                              hipStream_t stream)
{
    const float* x     = (const float*)d_in[0];
    const float* prot  = (const float*)d_in[1];
    const float* fb    = (const float*)d_in[2];
    const float* alpha = (const float*)d_in[3];
    const float* beta  = (const float*)d_in[4];
    float* out = (float*)d_out;

    float* xf    = (float*)d_ws;                 // Bn*Fn
    float* pfT   = xf + (size_t)Bn * Fn;         // Fn*Pn
    float* partI = pfT + (size_t)Fn * Pn;        // SB*BP
    float* partW = partI + (size_t)SB * BP;      // SB*BP

    dim3 gg(Fn / 64, (Bn + Pn) / 64);            // 8 x 18 = 144 blocks
    gemm_feat<<<gg, 256, 0, stream>>>(x, prot, fb, xf, pfT, 8);

    dim3 gm(Bn / 64, Pn / 32, SB);               // 16 x 4 x 8 = 512 blocks
    tversky_main<<<gm, 256, 0, stream>>>(xf, pfT, alpha, beta, partI, partW, 10);

    tversky_epi<<<BP / 256, 256, 0, stream>>>(partI, partW, out, 20);
}

// Round 8
// 38.227 us; speedup vs baseline: 5.6319x; 5.6319x over previous
//
#include <hip/hip_runtime.h>

#define Bn 1024
#define Pn 128
#define Fn 512
#define Dn 256
#define THETA 1e-7f

typedef _Float16 f16;
typedef f16 f16x8 __attribute__((ext_vector_type(8)));
typedef f16 f16x4 __attribute__((ext_vector_type(4)));
typedef f16 f16x2 __attribute__((ext_vector_type(2)));
typedef float f32x4 __attribute__((ext_vector_type(4)));

// ---------------------------------------------------------------------------
// K1: exact f32 GEMM [x; prototypes] @ fb^T (round-1 body, validated).
// Epilogue converts the EXACT f32 accumulators to f16 relu-values + masks:
//   RX/RP = (f16)relu(v),  BX/BPm = v>0 ? 1 : 0   (masks from exact f32!)
// All outputs row-major [row][Fn] f16.
// ---------------------------------------------------------------------------
__global__ __launch_bounds__(256)
void gemm_feat(const float* __restrict__ x, const float* __restrict__ prot,
               const float* __restrict__ fb,
               f16* __restrict__ RX, f16* __restrict__ BX,
               f16* __restrict__ RP, f16* __restrict__ BPm)
{
    __shared__ float As[64][68];
    __shared__ float Fs[64][68];
    const int tid = threadIdx.x;
    const int rb  = blockIdx.y * 64;
    const int cb  = blockIdx.x * 64;
    const int tx  = tid & 15;
    const int ty  = tid >> 4;
    const int lr  = tid >> 2;
    const int lk  = tid & 3;

    float acc[4][4] = {};

    for (int k0 = 0; k0 < Dn; k0 += 64) {
        #pragma unroll
        for (int q = 0; q < 4; ++q) {
            const int kk = lk + q * 4;
            const int r  = rb + lr;
            const float* asrc = (r < Bn) ? (x + (size_t)r * Dn)
                                         : (prot + (size_t)(r - Bn) * Dn);
            float4 av = *(const float4*)(asrc + k0 + kk * 4);
            float4 fv = *(const float4*)(fb + (size_t)(cb + lr) * Dn + k0 + kk * 4);
            As[kk*4+0][lr] = av.x; As[kk*4+1][lr] = av.y;
            As[kk*4+2][lr] = av.z; As[kk*4+3][lr] = av.w;
            Fs[kk*4+0][lr] = fv.x; Fs[kk*4+1][lr] = fv.y;
            Fs[kk*4+2][lr] = fv.z; Fs[kk*4+3][lr] = fv.w;
        }
        __syncthreads();
        #pragma unroll 8
        for (int k = 0; k < 64; ++k) {
            float4 a = *(const float4*)&As[k][ty * 4];
            float4 f = *(const float4*)&Fs[k][tx * 4];
            const float aa[4] = {a.x, a.y, a.z, a.w};
            const float ff[4] = {f.x, f.y, f.z, f.w};
            #pragma unroll
            for (int i = 0; i < 4; ++i)
                #pragma unroll
                for (int j = 0; j < 4; ++j)
                    acc[i][j] = fmaf(aa[i], ff[j], acc[i][j]);
        }
        __syncthreads();
    }

    #pragma unroll
    for (int i = 0; i < 4; ++i) {
        const int r = rb + ty * 4 + i;
        f16x4 rv, bv;
        #pragma unroll
        for (int j = 0; j < 4; ++j) {
            const float v = acc[i][j];
            rv[j] = (f16)fmaxf(v, 0.f);
            bv[j] = (v > 0.f) ? (f16)1 : (f16)0;
        }
        f16 *rd, *bd;
        size_t off;
        if (r < Bn) { rd = RX; bd = BX;  off = (size_t)r * Fn + cb + tx * 4; }
        else        { rd = RP; bd = BPm; off = (size_t)(r - Bn) * Fn + cb + tx * 4; }
        *(f16x4*)(rd + off) = rv;
        *(f16x4*)(bd + off) = bv;
    }
}

// ---------------------------------------------------------------------------
// K2: fused Tversky. Per block: 16b x 16p output tile, full F=512.
//  - waves 0,1: f16 MFMA over F-half w:  I = RX*RP^T, SXB = RX*BPm^T,
//    SPB = BX*RP^T  (A-frag: row=l&15, k=(l>>4)*8; B-frag: col=l&15;
//    C/D: col=l&15, row=(l>>4)*4+reg — validated in rounds 2/3).
//  - all 4 waves: M = sum_f max(min(rx,rp),0) via packed f16 min/max/add
//    (exact min/max; only adds round; f32 flush every 8 f). F-half = w>>1,
//    pair-block = w&1 (2 pairs per lane).
//  - LDS combine + in-block ratio epilogue (no third dispatch).
// Grid (Bn/16, Pn/16) = 512 blocks x 256 thr -> 2048 waves (2/SIMD).
// ---------------------------------------------------------------------------
__global__ __launch_bounds__(256)
void tversky_fused(const f16* __restrict__ RX, const f16* __restrict__ BX,
                   const f16* __restrict__ RP, const f16* __restrict__ BPm,
                   const float* __restrict__ alpha_p, const float* __restrict__ beta_p,
                   float* __restrict__ out)
{
    __shared__ float sI[2][256], sX[2][256], sP[2][256], sM[2][256];
    const int tid  = threadIdx.x;
    const int w    = tid >> 6;          // wave 0..3
    const int lane = tid & 63;
    const int bb   = blockIdx.x * 16;
    const int pb   = blockIdx.y * 16;

    // ---- MFMA half (waves 0,1) ----
    if (w < 2) {
        const int f0   = w * 256;
        const size_t abase = (size_t)(bb + (lane & 15)) * Fn + f0 + (lane >> 4) * 8;
        const size_t bbase = (size_t)(pb + (lane & 15)) * Fn + f0 + (lane >> 4) * 8;
        f32x4 aI = {}, aX = {}, aP = {};
        #pragma unroll
        for (int k0 = 0; k0 < 256; k0 += 32) {
            const f16x8 rx = *(const f16x8*)(RX  + abase + k0);
            const f16x8 bx = *(const f16x8*)(BX  + abase + k0);
            const f16x8 rp = *(const f16x8*)(RP  + bbase + k0);
            const f16x8 bp = *(const f16x8*)(BPm + bbase + k0);
            aI = __builtin_amdgcn_mfma_f32_16x16x32_f16(rx, rp, aI, 0, 0, 0);
            aX = __builtin_amdgcn_mfma_f32_16x16x32_f16(rx, bp, aX, 0, 0, 0);
            aP = __builtin_amdgcn_mfma_f32_16x16x32_f16(bx, rp, aP, 0, 0, 0);
        }
        #pragma unroll
        for (int i = 0; i < 4; ++i) {
            const int idx = ((lane >> 4) * 4 + i) * 16 + (lane & 15);
            sI[w][idx] = aI[i]; sX[w][idx] = aX[i]; sP[w][idx] = aP[i];
        }
    }

    // ---- M half (all 4 waves): F-half = w>>1, 2 pairs per lane ----
    {
        const int fh    = w >> 1;
        const int fbase = fh * 256;
        const int pidx0 = (w & 1) * 128 + lane * 2;
        const int b     = pidx0 >> 4;          // 0..15
        const int p0    = pidx0 & 15;          // even
        const f16* xrow  = RX + (size_t)(bb + b) * Fn + fbase;
        const f16* prow0 = RP + (size_t)(pb + p0) * Fn + fbase;
        const f16* prow1 = RP + (size_t)(pb + p0 + 1) * Fn + fbase;
        float m0 = 0.f, m1 = 0.f;
        const f16x8 kz = {};
        #pragma unroll 4
        for (int g = 0; g < 32; ++g) {
            const f16x8 xv  = *(const f16x8*)(xrow  + g * 8);
            const f16x8 pv0 = *(const f16x8*)(prow0 + g * 8);
            const f16x8 pv1 = *(const f16x8*)(prow1 + g * 8);
            f16x8 a = __builtin_elementwise_max(__builtin_elementwise_min(xv, pv0), kz);
            f16x8 c = __builtin_elementwise_max(__builtin_elementwise_min(xv, pv1), kz);
            f16x4 a4 = __builtin_shufflevector(a, a, 0, 1, 2, 3)
                     + __builtin_shufflevector(a, a, 4, 5, 6, 7);
            f16x4 c4 = __builtin_shufflevector(c, c, 0, 1, 2, 3)
                     + __builtin_shufflevector(c, c, 4, 5, 6, 7);
            f16x2 a2 = __builtin_shufflevector(a4, a4, 0, 1)
                     + __builtin_shufflevector(a4, a4, 2, 3);
            f16x2 c2 = __builtin_shufflevector(c4, c4, 0, 1)
                     + __builtin_shufflevector(c4, c4, 2, 3);
            m0 += (float)a2[0] + (float)a2[1];
            m1 += (float)c2[0] + (float)c2[1];
        }
        sM[fh][pidx0]     = m0;
        sM[fh][pidx0 + 1] = m1;
    }

    __syncthreads();

    // ---- epilogue: one output per thread ----
    {
        const float alpha = *alpha_p;
        const float beta  = *beta_p;
        const float I = sI[0][tid] + sI[1][tid];
        const float X = sX[0][tid] + sX[1][tid];
        const float P = sP[0][tid] + sP[1][tid];
        const float M = sM[0][tid] + sM[1][tid];
        const float W = alpha * (X - M) + beta * (P - M);
        const int row = tid >> 4, col = tid & 15;
        out[(size_t)(bb + row) * Pn + pb + col] = I / (I + W + THETA);
    }
}

extern "C" void kernel_launch(void* const* d_in, const int* in_sizes, int n_in,
                              void* d_out, int out_size, void* d_ws, size_t ws_size,
                              hipStream_t stream)
{
    const float* x     = (const float*)d_in[0];
    const float* prot  = (const float*)d_in[1];
    const float* fb    = (const float*)d_in[2];
    const float* alpha = (const float*)d_in[3];
    const float* beta  = (const float*)d_in[4];
    float* out = (float*)d_out;

    f16* RX  = (f16*)d_ws;                   // Bn*Fn
    f16* BX  = RX + (size_t)Bn * Fn;         // Bn*Fn
    f16* RP  = BX + (size_t)Bn * Fn;         // Pn*Fn
    f16* BPm = RP + (size_t)Pn * Fn;         // Pn*Fn

    dim3 gg(Fn / 64, (Bn + Pn) / 64);        // 8 x 18 = 144 blocks
    gemm_feat<<<gg, 256, 0, stream>>>(x, prot, fb, RX, BX, RP, BPm);

    dim3 gf(Bn / 16, Pn / 16);               // 64 x 8 = 512 blocks
    tversky_fused<<<gf, 256, 0, stream>>>(RX, BX, RP, BPm, alpha, beta, out);
}